// Round 18
// baseline (274.168 us; speedup 1.0000x reference)
//
#include <hip/hip_runtime.h>
#include <stdint.h>

typedef __attribute__((ext_vector_type(8))) short short8;
typedef __attribute__((ext_vector_type(4))) float f32x4;

constexpr int      BATCH    = 524288;
constexpr int      ARRAY_SZ = 262144;
constexpr uint64_t PRIME    = 2038074743ull;
constexpr uint32_t RANGE    = 262137u;          // ARRAY_SZ - 8 + 1
constexpr int      NMT      = BATCH / 16;       // 32768 M-tiles of 16 elements
// Sign-certainty bound, 2-split (hi+mid) MFMA vs sequential-fmaf reference
// (derivation in r17, verified absmax 0.0): total error < 5.4e-5 * Sum|x|,
// margin EPS = 8e-5. Flagged entries recomputed with the sequential fmaf
// chain proven bit-exact in rounds 1-17.
constexpr float    EPS      = 8e-5f;

__global__ __launch_bounds__(256, 2)
void lma_mfma9(const float* __restrict__ x,
               const float* __restrict__ hw,
               const float* __restrict__ lsh,
               const void* __restrict__ rnd_raw,
               float* __restrict__ out_idx,   // B*128 floats (idx as f32)
               float* __restrict__ out_val)   // B*64 floats
{
    // ONLY LDS use: T[n][i] = lsh^T as bf16 (exact: {-1,0,1}); 16B-unit XOR
    // swizzle (proven r10/r14/r16). 32768 B -> 4 blocks/CU by LDS.
    __shared__ unsigned short T[128 * 128];

    const int tid  = threadIdx.x;
    const int lane = tid & 63;
    const int wid  = __builtin_amdgcn_readfirstlane(tid >> 6);

    // --- hash constants: detect int64 vs int32 layout of random_numbers ---
    uint64_t HA, HB, HC0;
    {
        const uint64_t first8 = *reinterpret_cast<const uint64_t*>(rnd_raw);
        if (first8 == PRIME) {
            const long long* r64 = reinterpret_cast<const long long*>(rnd_raw);
            HA = (uint64_t)r64[1]; HB = (uint64_t)r64[2]; HC0 = (uint64_t)r64[3];
        } else {
            const int* r32 = reinterpret_cast<const int*>(rnd_raw);
            HA  = (uint64_t)(uint32_t)r32[1];
            HB  = (uint64_t)(uint32_t)r32[2];
            HC0 = (uint64_t)(uint32_t)r32[3];
        }
    }

    // --- stage T = bf16(lsh)^T, XOR-swizzled (one-time) ---
    for (int it = 0; it < 16; ++it) {
        const int flat4 = it * 256 + tid;            // 0..4095
        const int i  = flat4 >> 5;                   // input dim 0..127
        const int n4 = (flat4 & 31) << 2;            // output col base
        const f32x4 v = *reinterpret_cast<const f32x4*>(lsh + i * 128 + n4);
#pragma unroll
        for (int d = 0; d < 4; ++d) {
            const int n = n4 + d;
            T[n * 128 + (((i >> 3) ^ (n & 15)) << 3) + (i & 7)] =
                (unsigned short)(__float_as_uint(v[d]) >> 16);
        }
    }
    __syncthreads();   // only block barrier; T read-only afterwards

    const int r    = lane & 15;       // A/B fragment row (x row, T col)
    const int g    = lane >> 4;       // k-group
    const int e    = lane >> 2;       // phase-2 element (0..15)
    const int c4   = lane & 3;        // phase-2 chunk slot
    const int hf   = c4 & 1;          // col-half within a 16-col n8 block
    const int npar = c4 >> 1;         // n8 parity this lane consumes
    const int shb  = 16 * (e >> 2) + 8 * hf;   // bit offset in ballots
    const int sel  = e & 3;           // which reg's ballot holds row e
    const bool s0 = (sel == 0), s1 = (sel == 1), s2 = (sel == 2);

    // --- prologue: prefetch first tile's x fragment into loop-carried regs ---
    const int mt0 = blockIdx.x * 4 + wid;            // grid 2048 -> stride 8192
    f32x4 xp0, xp1, xp2, xp3, xp4, xp5, xp6, xp7;
    {
        const float* xn = x + (size_t)mt0 * 16 * 128 + r * 128 + g * 8;
        xp0 = *reinterpret_cast<const f32x4*>(xn);
        xp1 = *reinterpret_cast<const f32x4*>(xn + 4);
        xp2 = *reinterpret_cast<const f32x4*>(xn + 32);
        xp3 = *reinterpret_cast<const f32x4*>(xn + 36);
        xp4 = *reinterpret_cast<const f32x4*>(xn + 64);
        xp5 = *reinterpret_cast<const f32x4*>(xn + 68);
        xp6 = *reinterpret_cast<const f32x4*>(xn + 96);
        xp7 = *reinterpret_cast<const f32x4*>(xn + 100);
    }

#pragma unroll 1
    for (int mt = mt0; mt < NMT; mt += 8192) {
        const int Mb = mt * 16;

        f32x4 acc[8];
#pragma unroll
        for (int n8 = 0; n8 < 8; ++n8) acc[n8] = (f32x4)(0.0f);
        float asum = 0.0f;

        // ---- phase 1: exact 2-way split MFMA (r17-certified); x from regs ----
#pragma unroll
        for (int ks = 0; ks < 4; ++ks) {
            const f32x4 xa = (ks == 0) ? xp0 : (ks == 1) ? xp2 : (ks == 2) ? xp4 : xp6;
            const f32x4 xc = (ks == 0) ? xp1 : (ks == 1) ? xp3 : (ks == 2) ? xp5 : xp7;
            float xs[8] = {xa[0], xa[1], xa[2], xa[3], xc[0], xc[1], xc[2], xc[3]};
#pragma unroll
            for (int j = 0; j < 8; ++j) asum += fabsf(xs[j]);

            union { uint32_t u[4]; short8 v; } Ahi, Ami;
#pragma unroll
            for (int p = 0; p < 4; ++p) {
                const uint32_t b0 = __float_as_uint(xs[2 * p]);
                const uint32_t b1 = __float_as_uint(xs[2 * p + 1]);
                const uint32_t h0 = b0 & 0xFFFF0000u, h1 = b1 & 0xFFFF0000u;
                const float    t0 = xs[2 * p] - __uint_as_float(h0);
                const float    t1 = xs[2 * p + 1] - __uint_as_float(h1);
                const uint32_t m0 = __float_as_uint(t0) & 0xFFFF0000u;
                const uint32_t m1 = __float_as_uint(t1) & 0xFFFF0000u;
                Ahi.u[p] = h1 | (h0 >> 16);
                Ami.u[p] = m1 | (m0 >> 16);
            }
#pragma unroll
            for (int n8 = 0; n8 < 8; ++n8) {
                const short8 bf = *reinterpret_cast<const short8*>(
                    &T[(n8 * 16 + r) * 128 + (((ks * 4 + g) ^ r) << 3)]);
                acc[n8] = __builtin_amdgcn_mfma_f32_16x16x32_bf16(Ahi.v, bf, acc[n8], 0, 0, 0);
                acc[n8] = __builtin_amdgcn_mfma_f32_16x16x32_bf16(Ami.v, bf, acc[n8], 0, 0, 0);
            }
        }

        // ---- prefetch next tile's x; sched_barrier pins the issue point ----
        {
            const int mtn = (mt + 8192 < NMT) ? mt + 8192 : mt;
            const float* xn = x + (size_t)mtn * 16 * 128 + r * 128 + g * 8;
            xp0 = *reinterpret_cast<const f32x4*>(xn);
            xp1 = *reinterpret_cast<const f32x4*>(xn + 4);
            xp2 = *reinterpret_cast<const f32x4*>(xn + 32);
            xp3 = *reinterpret_cast<const f32x4*>(xn + 36);
            xp4 = *reinterpret_cast<const f32x4*>(xn + 64);
            xp5 = *reinterpret_cast<const f32x4*>(xn + 68);
            xp6 = *reinterpret_cast<const f32x4*>(xn + 96);
            xp7 = *reinterpret_cast<const f32x4*>(xn + 100);
        }
        __builtin_amdgcn_sched_barrier(0);

        // row-|x| sums over k-groups; bndr[reg] = bound for acc row g*4+reg
        asum += __shfl_xor(asum, 16);
        asum += __shfl_xor(asum, 32);
        float bndr[4];
#pragma unroll
        for (int reg = 0; reg < 4; ++reg)
            bndr[reg] = __shfl(asum, (lane >> 4) * 4 + reg) * EPS;

        // ---- ballot bit-transpose: sign + flag bytes, no LDS round-trip ----
        // Ballot (n8,reg) bit L = predicate of row gL*4+reg, col n8*16+rL.
        // Lane's task byte for chunk cc=2*n8+hf of element e sits at
        // bits [shb, shb+8) of the reg==e&3 ballot.
        uint32_t wsrp = 0, wflg = 0;
#pragma unroll
        for (int n8 = 0; n8 < 8; ++n8) {
            const unsigned long long sb0 = __ballot(acc[n8][0] > 0.0f);
            const unsigned long long sb1 = __ballot(acc[n8][1] > 0.0f);
            const unsigned long long sb2 = __ballot(acc[n8][2] > 0.0f);
            const unsigned long long sb3 = __ballot(acc[n8][3] > 0.0f);
            const unsigned long long fb0 = __ballot(fabsf(acc[n8][0]) <= bndr[0]);
            const unsigned long long fb1 = __ballot(fabsf(acc[n8][1]) <= bndr[1]);
            const unsigned long long fb2 = __ballot(fabsf(acc[n8][2]) <= bndr[2]);
            const unsigned long long fb3 = __ballot(fabsf(acc[n8][3]) <= bndr[3]);
            const unsigned long long sbx = s0 ? sb0 : s1 ? sb1 : s2 ? sb2 : sb3;
            const unsigned long long fbx = s0 ? fb0 : s1 ? fb1 : s2 ? fb2 : fb3;
            if ((n8 & 1) == npar) {
                const int mshift = ((n8 - npar) >> 1) * 8;   // task slot * 8
                wsrp |= (uint32_t)((sbx >> shb) & 0xffull) << mshift;
                wflg |= (uint32_t)((fbx >> shb) & 0xffull) << mshift;
            }
        }

        const size_t eg = (size_t)(Mb + e);
        float wv[4][8];

        // ---- phase 2: 4 tasks per lane (element e, chunk cc = c4 + 4m) ----
#pragma unroll
        for (int m = 0; m < 4; ++m) {
            const int cc  = c4 + 4 * m;          // global chunk 0..15
            const int cch = cc & 7;
            const int rep = cc >> 3;
            uint32_t srp = (wsrp >> (8 * m)) & 0xFFu;
            const uint32_t flg = (wflg >> (8 * m)) & 0xFFu;
            if (flg) {  // rare exact fallback: sequential fmaf, i = 0..127
                const float* xr = x + eg * 128;
                for (uint32_t fb = flg; fb; fb &= fb - 1) {
                    const int j = __builtin_ctz(fb);
                    const int k = cc * 8 + j;
                    float s = 0.0f;
#pragma unroll 4
                    for (int i8 = 0; i8 < 16; ++i8) {
                        const uint4 tb = *reinterpret_cast<const uint4*>(
                            &T[k * 128 + ((i8 ^ (k & 15)) << 3)]);
                        const f32x4 xA = *reinterpret_cast<const f32x4*>(xr + i8 * 8);
                        const f32x4 xB = *reinterpret_cast<const f32x4*>(xr + i8 * 8 + 4);
                        const uint32_t tu[4] = {tb.x, tb.y, tb.z, tb.w};
                        s = __builtin_fmaf(xA[0], __uint_as_float(tu[0] << 16), s);
                        s = __builtin_fmaf(xA[1], __uint_as_float(tu[0] & 0xFFFF0000u), s);
                        s = __builtin_fmaf(xA[2], __uint_as_float(tu[1] << 16), s);
                        s = __builtin_fmaf(xA[3], __uint_as_float(tu[1] & 0xFFFF0000u), s);
                        s = __builtin_fmaf(xB[0], __uint_as_float(tu[2] << 16), s);
                        s = __builtin_fmaf(xB[1], __uint_as_float(tu[2] & 0xFFFF0000u), s);
                        s = __builtin_fmaf(xB[2], __uint_as_float(tu[3] << 16), s);
                        s = __builtin_fmaf(xB[3], __uint_as_float(tu[3] & 0xFFFF0000u), s);
                    }
                    srp = (srp & ~(1u << j)) | ((s > 0.0f) ? (1u << j) : 0u);
                }
            }
            const uint64_t hh  = (HA * (uint64_t)srp + HB * (uint64_t)cch + HC0) % PRIME;
            const uint32_t loc = (uint32_t)hh % RANGE + (rep ? (uint32_t)ARRAY_SZ : 0u);

            const float f0 = (float)loc;
            float* oi = out_idx + eg * 128 + cc * 8;
            *reinterpret_cast<f32x4*>(oi)     = (f32x4){f0, f0 + 1.f, f0 + 2.f, f0 + 3.f};
            *reinterpret_cast<f32x4*>(oi + 4) = (f32x4){f0 + 4.f, f0 + 5.f, f0 + 6.f, f0 + 7.f};

#pragma unroll
            for (int j = 0; j < 8; ++j) wv[m][j] = hw[loc + j];
        }

        // ---- rep-average and out_val stores (tasks m and m+2 pair up) ----
#pragma unroll
        for (int m = 0; m < 2; ++m) {
            float* ov = out_val + eg * 64 + (c4 + 4 * m) * 8;
            *reinterpret_cast<f32x4*>(ov) =
                (f32x4){(wv[m][0] + wv[2 + m][0]) * 0.5f, (wv[m][1] + wv[2 + m][1]) * 0.5f,
                        (wv[m][2] + wv[2 + m][2]) * 0.5f, (wv[m][3] + wv[2 + m][3]) * 0.5f};
            *reinterpret_cast<f32x4*>(ov + 4) =
                (f32x4){(wv[m][4] + wv[2 + m][4]) * 0.5f, (wv[m][5] + wv[2 + m][5]) * 0.5f,
                        (wv[m][6] + wv[2 + m][6]) * 0.5f, (wv[m][7] + wv[2 + m][7]) * 0.5f};
        }
    }
}

extern "C" void kernel_launch(void* const* d_in, const int* in_sizes, int n_in,
                              void* d_out, int out_size, void* d_ws, size_t ws_size,
                              hipStream_t stream) {
    const float* x   = (const float*)d_in[0];
    const float* hw  = (const float*)d_in[1];
    const float* lsh = (const float*)d_in[2];
    const void*  rnd = (const void*)d_in[3];

    float* out_idx = (float*)d_out;
    float* out_val = out_idx + (size_t)BATCH * 128;

    lma_mfma9<<<2048, 256, 0, stream>>>(x, hw, lsh, rnd, out_idx, out_val);
}

// Round 19
// 271.959 us; speedup vs baseline: 1.0081x; 1.0081x over previous
//
#include <hip/hip_runtime.h>
#include <stdint.h>

typedef __attribute__((ext_vector_type(8))) short short8;
typedef __attribute__((ext_vector_type(4))) float f32x4;

constexpr int      BATCH    = 524288;
constexpr int      ARRAY_SZ = 262144;
constexpr uint64_t PRIME    = 2038074743ull;
constexpr uint32_t RANGE    = 262137u;          // ARRAY_SZ - 8 + 1
constexpr int      NMT      = BATCH / 16;       // 32768 M-tiles of 16 elements
// Sign-certainty bound, 2-split (hi+mid) MFMA vs sequential-fmaf reference
// (derivation in r17, verified absmax 0.0 r17/r18): total error < 5.4e-5 *
// Sum|x|, margin EPS = 8e-5. Flagged entries recomputed with the sequential
// fmaf chain proven bit-exact in rounds 1-18.
constexpr float    EPS      = 8e-5f;

__global__ __launch_bounds__(512, 2)
void lma_mfmaA(const float* __restrict__ x,
               const float* __restrict__ hw,
               const float* __restrict__ lsh,
               const void* __restrict__ rnd_raw,
               float* __restrict__ out_idx,   // B*128 floats (idx as f32)
               float* __restrict__ out_val)   // B*64 floats
{
    // ONLY LDS use: T[n][i] = lsh^T as bf16 (exact: {-1,0,1}); 16B-unit XOR
    // swizzle (proven r10-r18). 32768 B, shared by 8 waves.
    __shared__ unsigned short T[128 * 128];

    const int tid  = threadIdx.x;
    const int lane = tid & 63;
    const int wid  = __builtin_amdgcn_readfirstlane(tid >> 6);   // 0..7

    // --- hash constants: detect int64 vs int32 layout of random_numbers ---
    uint64_t HA, HB, HC0;
    {
        const uint64_t first8 = *reinterpret_cast<const uint64_t*>(rnd_raw);
        if (first8 == PRIME) {
            const long long* r64 = reinterpret_cast<const long long*>(rnd_raw);
            HA = (uint64_t)r64[1]; HB = (uint64_t)r64[2]; HC0 = (uint64_t)r64[3];
        } else {
            const int* r32 = reinterpret_cast<const int*>(rnd_raw);
            HA  = (uint64_t)(uint32_t)r32[1];
            HB  = (uint64_t)(uint32_t)r32[2];
            HC0 = (uint64_t)(uint32_t)r32[3];
        }
    }

    // --- stage T = bf16(lsh)^T, XOR-swizzled (one-time; 512 threads) ---
    for (int it = 0; it < 8; ++it) {
        const int flat4 = it * 512 + tid;            // 0..4095
        const int i  = flat4 >> 5;                   // input dim 0..127
        const int n4 = (flat4 & 31) << 2;            // output col base
        const f32x4 v = *reinterpret_cast<const f32x4*>(lsh + i * 128 + n4);
#pragma unroll
        for (int d = 0; d < 4; ++d) {
            const int n = n4 + d;
            T[n * 128 + (((i >> 3) ^ (n & 15)) << 3) + (i & 7)] =
                (unsigned short)(__float_as_uint(v[d]) >> 16);
        }
    }
    __syncthreads();   // only block barrier; T read-only afterwards

    const int r    = lane & 15;       // A/B fragment row (x row, T col)
    const int g    = lane >> 4;       // k-group
    const int e    = lane >> 2;       // phase-2 element (0..15)
    const int c4   = lane & 3;        // phase-2 chunk slot
    const int hf   = c4 & 1;          // col-half within a 16-col n8 block
    const int npar = c4 >> 1;         // n8 parity this lane consumes
    const int shb  = 16 * (e >> 2) + 8 * hf;   // bit offset in ballots
    const int sel  = e & 3;           // which reg's ballot holds row e
    const bool s0 = (sel == 0), s1 = (sel == 1), s2 = (sel == 2);

    // --- prologue: prefetch first tile's x fragment into loop-carried regs ---
    const int mt0 = blockIdx.x * 8 + wid;            // grid 2048 -> 16384 waves
    f32x4 xp0, xp1, xp2, xp3, xp4, xp5, xp6, xp7;
    {
        const float* xn = x + (size_t)mt0 * 16 * 128 + r * 128 + g * 8;
        xp0 = *reinterpret_cast<const f32x4*>(xn);
        xp1 = *reinterpret_cast<const f32x4*>(xn + 4);
        xp2 = *reinterpret_cast<const f32x4*>(xn + 32);
        xp3 = *reinterpret_cast<const f32x4*>(xn + 36);
        xp4 = *reinterpret_cast<const f32x4*>(xn + 64);
        xp5 = *reinterpret_cast<const f32x4*>(xn + 68);
        xp6 = *reinterpret_cast<const f32x4*>(xn + 96);
        xp7 = *reinterpret_cast<const f32x4*>(xn + 100);
    }

#pragma unroll 1
    for (int mt = mt0; mt < NMT; mt += 16384) {
        const int Mb = mt * 16;

        f32x4 acc[8];
#pragma unroll
        for (int n8 = 0; n8 < 8; ++n8) acc[n8] = (f32x4)(0.0f);
        float asum = 0.0f;

        // ---- phase 1: exact 2-way split MFMA (r17-certified); x from regs ----
#pragma unroll
        for (int ks = 0; ks < 4; ++ks) {
            const f32x4 xa = (ks == 0) ? xp0 : (ks == 1) ? xp2 : (ks == 2) ? xp4 : xp6;
            const f32x4 xc = (ks == 0) ? xp1 : (ks == 1) ? xp3 : (ks == 2) ? xp5 : xp7;
            float xs[8] = {xa[0], xa[1], xa[2], xa[3], xc[0], xc[1], xc[2], xc[3]};
#pragma unroll
            for (int j = 0; j < 8; ++j) asum += fabsf(xs[j]);

            union { uint32_t u[4]; short8 v; } Ahi, Ami;
#pragma unroll
            for (int p = 0; p < 4; ++p) {
                const uint32_t b0 = __float_as_uint(xs[2 * p]);
                const uint32_t b1 = __float_as_uint(xs[2 * p + 1]);
                const uint32_t h0 = b0 & 0xFFFF0000u, h1 = b1 & 0xFFFF0000u;
                const float    t0 = xs[2 * p] - __uint_as_float(h0);
                const float    t1 = xs[2 * p + 1] - __uint_as_float(h1);
                const uint32_t m0 = __float_as_uint(t0) & 0xFFFF0000u;
                const uint32_t m1 = __float_as_uint(t1) & 0xFFFF0000u;
                Ahi.u[p] = h1 | (h0 >> 16);
                Ami.u[p] = m1 | (m0 >> 16);
            }
#pragma unroll
            for (int n8 = 0; n8 < 8; ++n8) {
                const short8 bf = *reinterpret_cast<const short8*>(
                    &T[(n8 * 16 + r) * 128 + (((ks * 4 + g) ^ r) << 3)]);
                acc[n8] = __builtin_amdgcn_mfma_f32_16x16x32_bf16(Ahi.v, bf, acc[n8], 0, 0, 0);
                acc[n8] = __builtin_amdgcn_mfma_f32_16x16x32_bf16(Ami.v, bf, acc[n8], 0, 0, 0);
            }
        }

        // ---- prefetch next tile's x; sched_barrier pins the issue point ----
        {
            const int mtn = (mt + 16384 < NMT) ? mt + 16384 : mt;
            const float* xn = x + (size_t)mtn * 16 * 128 + r * 128 + g * 8;
            xp0 = *reinterpret_cast<const f32x4*>(xn);
            xp1 = *reinterpret_cast<const f32x4*>(xn + 4);
            xp2 = *reinterpret_cast<const f32x4*>(xn + 32);
            xp3 = *reinterpret_cast<const f32x4*>(xn + 36);
            xp4 = *reinterpret_cast<const f32x4*>(xn + 64);
            xp5 = *reinterpret_cast<const f32x4*>(xn + 68);
            xp6 = *reinterpret_cast<const f32x4*>(xn + 96);
            xp7 = *reinterpret_cast<const f32x4*>(xn + 100);
        }
        __builtin_amdgcn_sched_barrier(0);

        // row-|x| sums over k-groups; bndr[reg] = bound for acc row g*4+reg
        asum += __shfl_xor(asum, 16);
        asum += __shfl_xor(asum, 32);
        float bndr[4];
#pragma unroll
        for (int reg = 0; reg < 4; ++reg)
            bndr[reg] = __shfl(asum, (lane >> 4) * 4 + reg) * EPS;

        // ---- ballot bit-transpose: sign + flag bytes, no LDS round-trip ----
        uint32_t wsrp = 0, wflg = 0;
#pragma unroll
        for (int n8 = 0; n8 < 8; ++n8) {
            const unsigned long long sb0 = __ballot(acc[n8][0] > 0.0f);
            const unsigned long long sb1 = __ballot(acc[n8][1] > 0.0f);
            const unsigned long long sb2 = __ballot(acc[n8][2] > 0.0f);
            const unsigned long long sb3 = __ballot(acc[n8][3] > 0.0f);
            const unsigned long long fb0 = __ballot(fabsf(acc[n8][0]) <= bndr[0]);
            const unsigned long long fb1 = __ballot(fabsf(acc[n8][1]) <= bndr[1]);
            const unsigned long long fb2 = __ballot(fabsf(acc[n8][2]) <= bndr[2]);
            const unsigned long long fb3 = __ballot(fabsf(acc[n8][3]) <= bndr[3]);
            const unsigned long long sbx = s0 ? sb0 : s1 ? sb1 : s2 ? sb2 : sb3;
            const unsigned long long fbx = s0 ? fb0 : s1 ? fb1 : s2 ? fb2 : fb3;
            if ((n8 & 1) == npar) {
                const int mshift = ((n8 - npar) >> 1) * 8;   // task slot * 8
                wsrp |= (uint32_t)((sbx >> shb) & 0xffull) << mshift;
                wflg |= (uint32_t)((fbx >> shb) & 0xffull) << mshift;
            }
        }

        const size_t eg = (size_t)(Mb + e);
        float wv[4][8];

        // ---- phase 2: 4 tasks per lane (element e, chunk cc = c4 + 4m) ----
#pragma unroll
        for (int m = 0; m < 4; ++m) {
            const int cc  = c4 + 4 * m;          // global chunk 0..15
            const int cch = cc & 7;
            const int rep = cc >> 3;
            uint32_t srp = (wsrp >> (8 * m)) & 0xFFu;
            const uint32_t flg = (wflg >> (8 * m)) & 0xFFu;
            if (flg) {  // rare exact fallback: sequential fmaf, i = 0..127
                const float* xr = x + eg * 128;
                for (uint32_t fb = flg; fb; fb &= fb - 1) {
                    const int j = __builtin_ctz(fb);
                    const int k = cc * 8 + j;
                    float s = 0.0f;
#pragma unroll 4
                    for (int i8 = 0; i8 < 16; ++i8) {
                        const uint4 tb = *reinterpret_cast<const uint4*>(
                            &T[k * 128 + ((i8 ^ (k & 15)) << 3)]);
                        const f32x4 xA = *reinterpret_cast<const f32x4*>(xr + i8 * 8);
                        const f32x4 xB = *reinterpret_cast<const f32x4*>(xr + i8 * 8 + 4);
                        const uint32_t tu[4] = {tb.x, tb.y, tb.z, tb.w};
                        s = __builtin_fmaf(xA[0], __uint_as_float(tu[0] << 16), s);
                        s = __builtin_fmaf(xA[1], __uint_as_float(tu[0] & 0xFFFF0000u), s);
                        s = __builtin_fmaf(xA[2], __uint_as_float(tu[1] << 16), s);
                        s = __builtin_fmaf(xA[3], __uint_as_float(tu[1] & 0xFFFF0000u), s);
                        s = __builtin_fmaf(xB[0], __uint_as_float(tu[2] << 16), s);
                        s = __builtin_fmaf(xB[1], __uint_as_float(tu[2] & 0xFFFF0000u), s);
                        s = __builtin_fmaf(xB[2], __uint_as_float(tu[3] << 16), s);
                        s = __builtin_fmaf(xB[3], __uint_as_float(tu[3] & 0xFFFF0000u), s);
                    }
                    srp = (srp & ~(1u << j)) | ((s > 0.0f) ? (1u << j) : 0u);
                }
            }
            const uint64_t hh  = (HA * (uint64_t)srp + HB * (uint64_t)cch + HC0) % PRIME;
            const uint32_t loc = (uint32_t)hh % RANGE + (rep ? (uint32_t)ARRAY_SZ : 0u);

            const float f0 = (float)loc;
            float* oi = out_idx + eg * 128 + cc * 8;
            *reinterpret_cast<f32x4*>(oi)     = (f32x4){f0, f0 + 1.f, f0 + 2.f, f0 + 3.f};
            *reinterpret_cast<f32x4*>(oi + 4) = (f32x4){f0 + 4.f, f0 + 5.f, f0 + 6.f, f0 + 7.f};

#pragma unroll
            for (int j = 0; j < 8; ++j) wv[m][j] = hw[loc + j];
        }

        // ---- rep-average and out_val stores (tasks m and m+2 pair up) ----
#pragma unroll
        for (int m = 0; m < 2; ++m) {
            float* ov = out_val + eg * 64 + (c4 + 4 * m) * 8;
            *reinterpret_cast<f32x4*>(ov) =
                (f32x4){(wv[m][0] + wv[2 + m][0]) * 0.5f, (wv[m][1] + wv[2 + m][1]) * 0.5f,
                        (wv[m][2] + wv[2 + m][2]) * 0.5f, (wv[m][3] + wv[2 + m][3]) * 0.5f};
            *reinterpret_cast<f32x4*>(ov + 4) =
                (f32x4){(wv[m][4] + wv[2 + m][4]) * 0.5f, (wv[m][5] + wv[2 + m][5]) * 0.5f,
                        (wv[m][6] + wv[2 + m][6]) * 0.5f, (wv[m][7] + wv[2 + m][7]) * 0.5f};
        }
    }
}

extern "C" void kernel_launch(void* const* d_in, const int* in_sizes, int n_in,
                              void* d_out, int out_size, void* d_ws, size_t ws_size,
                              hipStream_t stream) {
    const float* x   = (const float*)d_in[0];
    const float* hw  = (const float*)d_in[1];
    const float* lsh = (const float*)d_in[2];
    const void*  rnd = (const void*)d_in[3];

    float* out_idx = (float*)d_out;
    float* out_val = out_idx + (size_t)BATCH * 128;

    lma_mfmaA<<<2048, 512, 0, stream>>>(x, hw, lsh, rnd, out_idx, out_val);
}